// Round 2
// baseline (1073.128 us; speedup 1.0000x reference)
//
#include <hip/hip_runtime.h>

typedef unsigned short u16;
typedef unsigned int u32;
typedef __attribute__((ext_vector_type(8))) short bf16x8;
typedef __attribute__((ext_vector_type(4))) float f32x4;

#define N_NODES 10000
#define E_EDGES 640000

static __device__ __forceinline__ float b2f(u16 u) {
  union { u32 i; float f; } x; x.i = ((u32)u) << 16; return x.f;
}
static __device__ __forceinline__ u16 f2b(float f) {
  union { float f; u32 i; } x; x.f = f;
  u32 r = x.i + 0x7FFF + ((x.i >> 16) & 1);   // RNE
  return (u16)(r >> 16);
}
// dtype-flagged load: f32 ? float : bf16
static __device__ __forceinline__ float ldf(const void* p, size_t i, int f32) {
  return f32 ? ((const float*)p)[i] : b2f(((const u16*)p)[i]);
}

// ---------------- dtype detect: bf16 data has no exponent >= 140; fp32 low-halves do ----------------
__global__ __launch_bounds__(256) void detect_kernel(const u16* __restrict__ x, int* __restrict__ flag) {
  __shared__ int cnt_s;
  if (threadIdx.x == 0) cnt_s = 0;
  __syncthreads();
  int c = 0;
  for (int i = threadIdx.x; i < 4096; i += 256) {
    int e = (x[i] >> 7) & 255;
    if (e >= 140) c++;
  }
  atomicAdd(&cnt_s, c);
  __syncthreads();
  if (threadIdx.x == 0) flag[0] = (cnt_s > 64) ? 1 : 0;
}

// ---------------- CSR build keyed by (dst*8 + rel) ----------------
__global__ void hist_kernel(const int* __restrict__ ei, const int* __restrict__ et,
                            int E, int* __restrict__ cnt) {
  int e = blockIdx.x * 256 + threadIdx.x;
  if (e < E) atomicAdd(&cnt[ei[E + e] * 8 + et[e]], 1);
}

__global__ __launch_bounds__(256) void scan_kernel(const int* __restrict__ cnt,
                                                   int* __restrict__ offs,
                                                   int* __restrict__ cursor, int N) {
  __shared__ int tmp[256];
  const int t = threadIdx.x;
  const int CH = (N + 255) / 256;
  const int base = t * CH;
  int s = 0;
  for (int j = 0; j < CH; j++) { int p = base + j; if (p < N) s += cnt[p]; }
  tmp[t] = s;
  __syncthreads();
  for (int od = 1; od < 256; od <<= 1) {
    int a = (t >= od) ? tmp[t - od] : 0;
    __syncthreads();
    tmp[t] += a;
    __syncthreads();
  }
  int run = tmp[t] - s;   // exclusive prefix
  for (int j = 0; j < CH; j++) {
    int p = base + j;
    if (p < N) { offs[p] = run; cursor[p] = run; run += cnt[p]; }
  }
  if (t == 255) offs[N] = tmp[255];
}

__global__ void bucket_kernel(const int* __restrict__ ei, const int* __restrict__ et,
                              int E, int* __restrict__ cursor, int* __restrict__ bucket) {
  int e = blockIdx.x * 256 + threadIdx.x;
  if (e < E) {
    int seg = ei[E + e] * 8 + et[e];
    int pos = atomicAdd(&cursor[seg], 1);
    bucket[pos] = ei[e];   // src only; relation is the segment index
  }
}

// ---------------- transpose (emb -> embT as bf16) ----------------
__global__ void transpose_kernel(const void* __restrict__ in, u16* __restrict__ out,
                                 int R, int C, const int* __restrict__ dflag) {
  __shared__ u16 tile[64][65];
  const int f = dflag[0];
  int r0 = blockIdx.x * 64, c0 = blockIdx.y * 64;
  int t = threadIdx.x;
  #pragma unroll
  for (int k = 0; k < 16; k++) {
    int lin = t + k * 256; int rr = lin >> 6, cc = lin & 63;
    int gr = r0 + rr;
    tile[rr][cc] = (gr < R) ? f2b(ldf(in, (size_t)gr * C + c0 + cc, f)) : (u16)0;
  }
  __syncthreads();
  #pragma unroll
  for (int k = 0; k < 16; k++) {
    int lin = t + k * 256; int rr = lin >> 6, cc = lin & 63;
    int gc = r0 + cc;
    if (gc < R) out[(size_t)(c0 + rr) * R + gc] = tile[cc][rr];
  }
}

// ---------------- W-prep (layer 1): WT[o][kcat], kcat = r*I+i (basis rows) then I root rows ----------------
template<int I, int O>
__global__ void wprep_kernel(const void* __restrict__ comp, const void* __restrict__ basis,
                             const void* __restrict__ root, u16* __restrict__ WT,
                             const int* __restrict__ dflag) {
  const int Kcat = 9 * I;
  const int f = dflag[0];
  int idx = blockIdx.x * 256 + threadIdx.x;
  if (idx >= Kcat * O) return;
  int o = idx % O;
  int kc = idx / O;
  float v;
  if (kc < 8 * I) {
    int r = kc / I, i = kc % I;
    float s = 0.f;
    #pragma unroll
    for (int b = 0; b < 8; b++)
      s += ldf(comp, r * 8 + b, f) * ldf(basis, ((size_t)b * I + i) * O + o, f);
    v = s;
  } else {
    int i = kc - 8 * I;
    v = ldf(root, (size_t)i * O + o, f);
  }
  WT[(size_t)o * Kcat + kc] = f2b(v);
}

// ---------------- W-prep (layer 2, transposed-cat): WT[ocat][k], ocat = r*O+o (r<8), root at r=8 ----------------
template<int I, int O>
__global__ void wprep_t_kernel(const void* __restrict__ comp, const void* __restrict__ basis,
                               const void* __restrict__ root, u16* __restrict__ WT,
                               const int* __restrict__ dflag) {
  const int f = dflag[0];
  int idx = blockIdx.x * 256 + threadIdx.x;
  if (idx >= 9 * O * I) return;
  int k = idx % I;
  int ocat = idx / I;
  int r = ocat / O, o = ocat % O;
  float v;
  if (r < 8) {
    float s = 0.f;
    #pragma unroll
    for (int b = 0; b < 8; b++)
      s += ldf(comp, r * 8 + b, f) * ldf(basis, ((size_t)b * I + k) * O + o, f);
    v = s;
  } else {
    v = ldf(root, (size_t)k * O + o, f);
  }
  WT[(size_t)ocat * I + k] = f2b(v);
}

// ---------------- layer-1 gather: per-(dst,rel) register accumulate, no LDS ----------------
// s row layout: [r*128 + t] = mean over relation-r in-edges; [1024 + t] = own h0 row
__global__ void gather1_kernel(const u16* __restrict__ h, const int* __restrict__ offs,
                               const int* __restrict__ bucket, u16* __restrict__ s, int node0) {
  const int d = node0 + blockIdx.x, t = threadIdx.x;   // 128 threads
  const int sb = d * 8;
  const int b0 = offs[sb], bend = offs[sb + 8];
  const float inv = 1.0f / (float)((bend - b0) > 1 ? (bend - b0) : 1);
  const size_t base = (size_t)blockIdx.x * 1152;
  #pragma unroll
  for (int r = 0; r < 8; r++) {
    int j = offs[sb + r], j1 = offs[sb + r + 1];
    float a0 = 0.f, a1 = 0.f;
    for (; j + 1 < j1; j += 2) {
      int sA = bucket[j], sB = bucket[j + 1];
      a0 += b2f(h[(size_t)sA * 128 + t]);
      a1 += b2f(h[(size_t)sB * 128 + t]);
    }
    if (j < j1) a0 += b2f(h[(size_t)bucket[j] * 128 + t]);
    s[base + r * 128 + t] = f2b((a0 + a1) * inv);
  }
  s[base + 1024 + t] = h[(size_t)d * 128 + t];
}

// ---------------- layer-2 aggregate: h2 = relu(mean_e hb2[src_e, rel_e*128+t] + root-slice + bias) ----------------
__global__ void agg2_kernel(const u16* __restrict__ hb, const int* __restrict__ offs,
                            const int* __restrict__ bucket, const void* __restrict__ bias,
                            u16* __restrict__ h2, const int* __restrict__ dflag) {
  const int d = blockIdx.x, t = threadIdx.x;   // 128 threads
  const int sb = d * 8;
  const int b0 = offs[sb], bend = offs[sb + 8];
  const float inv = 1.0f / (float)((bend - b0) > 1 ? (bend - b0) : 1);
  float a0 = 0.f, a1 = 0.f;
  #pragma unroll
  for (int r = 0; r < 8; r++) {
    int j = offs[sb + r], j1 = offs[sb + r + 1];
    const size_t co = (size_t)(r * 128 + t);
    for (; j + 1 < j1; j += 2) {
      int sA = bucket[j], sB = bucket[j + 1];
      a0 += b2f(hb[(size_t)sA * 1152 + co]);
      a1 += b2f(hb[(size_t)sB * 1152 + co]);
    }
    if (j < j1) a0 += b2f(hb[(size_t)bucket[j] * 1152 + co]);
  }
  float v = (a0 + a1) * inv + b2f(hb[(size_t)d * 1152 + 1024 + t]) + ldf(bias, t, dflag[0]);
  h2[(size_t)d * 128 + t] = f2b(v > 0.f ? v : 0.f);
}

// ---------------- MFMA GEMM: partials[split] = A[M,K] * BT[Nout,K]^T, 128x128 tiles ----------------
// A is bf16 unless (dflagA && dflagA[0]) -> fp32 elements, converted during staging.
__global__ __launch_bounds__(256) void gemm_kernel(
    const void* __restrict__ A, int lda,
    const u16* __restrict__ BT, int ldbt,
    int M, int Nout, int K,
    int tiles_per_split, int ktiles_total,
    float* __restrict__ partials,
    const int* __restrict__ dflagA) {
  __shared__ __align__(16) u16 As[128 * 32];
  __shared__ __align__(16) u16 Bs[128 * 32];
  const int f32A = dflagA ? dflagA[0] : 0;
  const int tid = threadIdx.x;
  const int wave = tid >> 6;
  const int lane = tid & 63;
  const int quad = lane >> 4;
  const int l16 = lane & 15;
  const int m0 = blockIdx.x * 128;
  const int n0 = blockIdx.y * 128;
  const int split = blockIdx.z;
  const int wm = (wave >> 1) * 64;
  const int wn = (wave & 1) * 64;

  int kt0 = split * tiles_per_split;
  int kt1 = kt0 + tiles_per_split;
  if (kt1 > ktiles_total) kt1 = ktiles_total;

  f32x4 acc[4][4];
  #pragma unroll
  for (int mi = 0; mi < 4; mi++)
    #pragma unroll
    for (int ni = 0; ni < 4; ni++) {
      f32x4 z = {0.f, 0.f, 0.f, 0.f};
      acc[mi][ni] = z;
    }

  for (int kt = kt0; kt < kt1; ++kt) {
    const int k0 = kt * 32;
    __syncthreads();
    #pragma unroll
    for (int i = 0; i < 2; ++i) {
      int c = tid + i * 256;
      int row = c >> 2, kc = c & 3;
      int kpos = k0 + kc * 8;
      // B tile (always bf16)
      uint4 vb = {0u, 0u, 0u, 0u};
      if (kpos < K) vb = *(const uint4*)(BT + (size_t)(n0 + row) * ldbt + kpos);
      *(uint4*)&Bs[(size_t)c * 8] = vb;
      // A tile
      uint4 va = {0u, 0u, 0u, 0u};
      if (kpos < K) {
        int ga = m0 + row; if (ga > M - 1) ga = M - 1;
        if (!f32A) {
          va = *(const uint4*)((const u16*)A + (size_t)ga * lda + kpos);
        } else {
          const float* Af = (const float*)A + (size_t)ga * lda + kpos;
          float4 f0 = ((const float4*)Af)[0];
          float4 f1 = ((const float4*)Af)[1];
          va.x = (u32)f2b(f0.x) | ((u32)f2b(f0.y) << 16);
          va.y = (u32)f2b(f0.z) | ((u32)f2b(f0.w) << 16);
          va.z = (u32)f2b(f1.x) | ((u32)f2b(f1.y) << 16);
          va.w = (u32)f2b(f1.z) | ((u32)f2b(f1.w) << 16);
        }
      }
      *(uint4*)&As[(size_t)c * 8] = va;
    }
    __syncthreads();

    bf16x8 af[4], bfr[4];
    #pragma unroll
    for (int mi = 0; mi < 4; mi++)
      af[mi] = *(const bf16x8*)&As[(size_t)(wm + mi * 16 + l16) * 32 + quad * 8];
    #pragma unroll
    for (int ni = 0; ni < 4; ni++)
      bfr[ni] = *(const bf16x8*)&Bs[(size_t)(wn + ni * 16 + l16) * 32 + quad * 8];
    #pragma unroll
    for (int mi = 0; mi < 4; mi++)
      #pragma unroll
      for (int ni = 0; ni < 4; ni++)
        acc[mi][ni] = __builtin_amdgcn_mfma_f32_16x16x32_bf16(af[mi], bfr[ni], acc[mi][ni], 0, 0, 0);
  }

  #pragma unroll
  for (int mi = 0; mi < 4; mi++)
    #pragma unroll
    for (int ni = 0; ni < 4; ni++)
      #pragma unroll
      for (int jj = 0; jj < 4; jj++) {
        int row = m0 + wm + mi * 16 + quad * 4 + jj;
        int col = n0 + wn + ni * 16 + l16;
        if (row < M) partials[((size_t)split * M + row) * Nout + col] = acc[mi][ni][jj];
      }
}

// ---------------- MFMA GEMM, single-pass, direct bf16 output (layer-2 transform) ----------------
__global__ __launch_bounds__(256) void gemm_direct_kernel(
    const u16* __restrict__ A, int lda,
    const u16* __restrict__ BT, int ldbt,
    int M, int Nout, int K,
    u16* __restrict__ out) {
  __shared__ __align__(16) u16 As[128 * 32];
  __shared__ __align__(16) u16 Bs[128 * 32];
  const int tid = threadIdx.x;
  const int wave = tid >> 6;
  const int lane = tid & 63;
  const int quad = lane >> 4;
  const int l16 = lane & 15;
  const int m0 = blockIdx.x * 128;
  const int n0 = blockIdx.y * 128;
  const int wm = (wave >> 1) * 64;
  const int wn = (wave & 1) * 64;

  f32x4 acc[4][4];
  #pragma unroll
  for (int mi = 0; mi < 4; mi++)
    #pragma unroll
    for (int ni = 0; ni < 4; ni++) {
      f32x4 z = {0.f, 0.f, 0.f, 0.f};
      acc[mi][ni] = z;
    }

  const int ktiles = K >> 5;
  for (int kt = 0; kt < ktiles; ++kt) {
    const int k0 = kt * 32;
    __syncthreads();
    #pragma unroll
    for (int i = 0; i < 2; ++i) {
      int c = tid + i * 256;
      int row = c >> 2, kc = c & 3;
      int kpos = k0 + kc * 8;
      uint4 vb = *(const uint4*)(BT + (size_t)(n0 + row) * ldbt + kpos);
      *(uint4*)&Bs[(size_t)c * 8] = vb;
      int ga = m0 + row; if (ga > M - 1) ga = M - 1;
      uint4 va = *(const uint4*)(A + (size_t)ga * lda + kpos);
      *(uint4*)&As[(size_t)c * 8] = va;
    }
    __syncthreads();

    bf16x8 af[4], bfr[4];
    #pragma unroll
    for (int mi = 0; mi < 4; mi++)
      af[mi] = *(const bf16x8*)&As[(size_t)(wm + mi * 16 + l16) * 32 + quad * 8];
    #pragma unroll
    for (int ni = 0; ni < 4; ni++)
      bfr[ni] = *(const bf16x8*)&Bs[(size_t)(wn + ni * 16 + l16) * 32 + quad * 8];
    #pragma unroll
    for (int mi = 0; mi < 4; mi++)
      #pragma unroll
      for (int ni = 0; ni < 4; ni++)
        acc[mi][ni] = __builtin_amdgcn_mfma_f32_16x16x32_bf16(af[mi], bfr[ni], acc[mi][ni], 0, 0, 0);
  }

  #pragma unroll
  for (int mi = 0; mi < 4; mi++)
    #pragma unroll
    for (int ni = 0; ni < 4; ni++)
      #pragma unroll
      for (int jj = 0; jj < 4; jj++) {
        int row = m0 + wm + mi * 16 + quad * 4 + jj;
        int col = n0 + wn + ni * 16 + l16;
        if (row < M) out[(size_t)row * Nout + col] = f2b(acc[mi][ni][jj]);
      }
}

// ---------------- reduce splits + optional bias + relu -> bf16 ----------------
__global__ void reduce_kernel(const float* __restrict__ partials, int S, int count,
                              int nmask, const void* __restrict__ bias, u16* __restrict__ out,
                              const int* __restrict__ dflag) {
  int idx = blockIdx.x * 256 + threadIdx.x;
  if (idx >= count) return;
  float s = 0.f;
  for (int z = 0; z < S; z++) s += partials[(size_t)z * count + idx];
  if (bias) s += ldf(bias, idx & nmask, dflag[0]);
  s = s > 0.f ? s : 0.f;
  out[idx] = f2b(s);
}

// ---------------- decoder: softmax(h2 @ wdec); output dtype follows flag ----------------
__global__ __launch_bounds__(256) void decoder_kernel(const u16* __restrict__ h2,
                                                      const void* __restrict__ wdec,
                                                      void* __restrict__ out,
                                                      const int* __restrict__ dflag) {
  __shared__ float w[128 * 32];
  __shared__ float hrow[4][128];
  const int f = dflag[0];
  int t = threadIdx.x;
  for (int i = t; i < 128 * 32; i += 256) w[i] = ldf(wdec, i, f);
  int wv = t >> 6, lane = t & 63;
  int n = blockIdx.x * 4 + wv;   // grid 2500 * 4 waves = 10000 exactly
  hrow[wv][lane * 2]     = b2f(h2[(size_t)n * 128 + lane * 2]);
  hrow[wv][lane * 2 + 1] = b2f(h2[(size_t)n * 128 + lane * 2 + 1]);
  __syncthreads();
  int half = lane >> 5, c = lane & 31;
  float sum = 0.f;
  #pragma unroll 8
  for (int k = 0; k < 64; k++) sum += hrow[wv][half * 64 + k] * w[(half * 64 + k) * 32 + c];
  sum += __shfl_xor(sum, 32);
  float mx = sum;
  #pragma unroll
  for (int m = 16; m >= 1; m >>= 1) mx = fmaxf(mx, __shfl_xor(mx, m));
  float e = __expf(sum - mx);
  float tot = e;
  #pragma unroll
  for (int m = 16; m >= 1; m >>= 1) tot += __shfl_xor(tot, m);
  float p = e / tot;
  if (half == 0) {
    if (f) ((float*)out)[(size_t)n * 32 + c] = p;
    else   ((u16*)out)[(size_t)n * 32 + c] = f2b(p);
  }
}

extern "C" void kernel_launch(void* const* d_in, const int* in_sizes, int n_in,
                              void* d_out, int out_size, void* d_ws, size_t ws_size,
                              hipStream_t stream) {
  const void* x      = d_in[0];
  const int* ei      = (const int*)d_in[1];
  const int* et      = (const int*)d_in[2];
  const void* emb    = d_in[3];
  const void* comp1  = d_in[4];
  const void* basis1 = d_in[5];
  const void* root1  = d_in[6];
  const void* bias1  = d_in[7];
  const void* comp2  = d_in[8];
  const void* basis2 = d_in[9];
  const void* root2  = d_in[10];
  const void* bias2  = d_in[11];
  const void* wdec   = d_in[12];

  const int N = N_NODES, E = E_EDGES;
  const int NSEG = N * 8;
  auto AL = [](size_t b) -> size_t { return (b + 255) & ~(size_t)255; };

  // ---- persistent arena ----
  char* base = (char*)d_ws;
  size_t off = 0;
  auto alloc = [&](size_t b) -> char* { char* p = base + off; off += AL(b); return p; };
  int* dflag  = (int*)alloc(4);
  int* offs   = (int*)alloc((size_t)(NSEG + 1) * 4);
  int* bucket = (int*)alloc((size_t)E * 4);
  u16* h0 = (u16*)alloc((size_t)N * 128 * 2);
  u16* h1 = (u16*)alloc((size_t)N * 256 * 2);
  u16* h2 = (u16*)alloc((size_t)N * 128 * 2);
  char* pool = base + off;
  size_t pool_sz = (ws_size > off) ? (ws_size - off) : 0;

  // ---- adaptive sizing (constant given ws_size -> graph-safe) ----
  int spA = 8;   // stage-A K splits; needs embT + spA*5.12MB
  while (spA > 1 && AL((size_t)128 * N * 2) + (size_t)spA * N * 128 * 4 > pool_sz) spA >>= 1;
  int nchunks = 1;
  while (nchunks < 32) {
    int Mc = (N + nchunks - 1) / nchunks;
    size_t reqL1 = AL((size_t)256 * 1152 * 2) + AL((size_t)Mc * 1152 * 2) + (size_t)2 * Mc * 256 * 4;
    if (reqL1 <= pool_sz) break;
    nchunks <<= 1;
  }
  const int Mc = (N + nchunks - 1) / nchunks;
  const int z1 = 2;

  // ---- dtype detect ----
  detect_kernel<<<1, 256, 0, stream>>>((const u16*)x, dflag);

  // ---- CSR build keyed by (dst,rel); cnt/cursor transient in pool ----
  int* cnt    = (int*)pool;
  int* cursor = (int*)(pool + AL((size_t)NSEG * 4));
  hipMemsetAsync(cnt, 0, (size_t)NSEG * 4, stream);
  hist_kernel<<<(E + 255) / 256, 256, 0, stream>>>(ei, et, E, cnt);
  scan_kernel<<<1, 256, 0, stream>>>(cnt, offs, cursor, NSEG);
  bucket_kernel<<<(E + 255) / 256, 256, 0, stream>>>(ei, et, E, cursor, bucket);

  // ---- stage A: h0 = relu(x @ emb) ----
  {
    u16* embT = (u16*)pool;
    float* pA = (float*)(pool + AL((size_t)128 * N * 2));
    transpose_kernel<<<dim3((N + 63) / 64, 2), 256, 0, stream>>>(emb, embT, N, 128, dflag);
    int ktt = (N + 31) / 32;                 // 313
    int tps = (ktt + spA - 1) / spA;
    gemm_kernel<<<dim3((N + 127) / 128, 1, spA), 256, 0, stream>>>(
        x, N, embT, N, N, 128, N, tps, ktt, pA, dflag);
    reduce_kernel<<<(N * 128 + 255) / 256, 256, 0, stream>>>(
        pA, spA, N * 128, 127, (const void*)nullptr, h0, dflag);
  }

  // ---- layer 1: gather-then-transform, I=128, O=256, Kcat=1152 ----
  {
    u16* WT1 = (u16*)pool;
    char* chunkbase = pool + AL((size_t)256 * 1152 * 2);
    wprep_kernel<128, 256><<<(1152 * 256 + 255) / 256, 256, 0, stream>>>(comp1, basis1, root1, WT1, dflag);
    for (int c = 0; c < nchunks; c++) {
      int node0 = c * Mc;
      int rows = N - node0; if (rows > Mc) rows = Mc;
      if (rows <= 0) break;
      u16* s1 = (u16*)chunkbase;
      float* p1 = (float*)(chunkbase + AL((size_t)Mc * 1152 * 2));
      gather1_kernel<<<rows, 128, 0, stream>>>(h0, offs, bucket, s1, node0);
      gemm_kernel<<<dim3((rows + 127) / 128, 2, z1), 256, 0, stream>>>(
          s1, 1152, WT1, 1152, rows, 256, 1152, (36 + z1 - 1) / z1, 36, p1, (const int*)nullptr);
      reduce_kernel<<<(rows * 256 + 255) / 256, 256, 0, stream>>>(
          p1, z1, rows * 256, 255, bias1, h1 + (size_t)node0 * 256, dflag);
    }
  }

  // ---- layer 2: transform-then-gather. hb2 = h1 @ WTcat2 ([N,1152] bf16), then edge aggregate ----
  {
    u16* WT2b = (u16*)pool;                                   // [1152][256]
    u16* hb2  = (u16*)(pool + AL((size_t)1152 * 256 * 2));    // [N][1152]
    wprep_t_kernel<256, 128><<<(1152 * 256 + 255) / 256, 256, 0, stream>>>(comp2, basis2, root2, WT2b, dflag);
    gemm_direct_kernel<<<dim3((N + 127) / 128, 9), 256, 0, stream>>>(
        h1, 256, WT2b, 256, N, 1152, 256, hb2);
    agg2_kernel<<<N, 128, 0, stream>>>(hb2, offs, bucket, bias2, h2, dflag);
  }

  // ---- decoder + softmax ----
  decoder_kernel<<<N / 4, 256, 0, stream>>>(h2, wdec, d_out, dflag);
}

// Round 3
// 899.305 us; speedup vs baseline: 1.1933x; 1.1933x over previous
//
#include <hip/hip_runtime.h>

typedef unsigned short u16;
typedef unsigned int u32;
typedef __attribute__((ext_vector_type(8))) short bf16x8;
typedef __attribute__((ext_vector_type(4))) float f32x4;

#define N_NODES 10000
#define E_EDGES 640000

static __device__ __forceinline__ float b2f(u16 u) {
  union { u32 i; float f; } x; x.i = ((u32)u) << 16; return x.f;
}
static __device__ __forceinline__ u16 f2b(float f) {
  union { float f; u32 i; } x; x.f = f;
  u32 r = x.i + 0x7FFF + ((x.i >> 16) & 1);   // RNE
  return (u16)(r >> 16);
}
// dtype-flagged load: f32 ? float : bf16
static __device__ __forceinline__ float ldf(const void* p, size_t i, int f32) {
  return f32 ? ((const float*)p)[i] : b2f(((const u16*)p)[i]);
}

// ---------------- dtype detect: bf16 data has no exponent >= 140; fp32 low-halves do ----------------
__global__ __launch_bounds__(256) void detect_kernel(const u16* __restrict__ x, int* __restrict__ flag) {
  __shared__ int cnt_s;
  if (threadIdx.x == 0) cnt_s = 0;
  __syncthreads();
  int c = 0;
  for (int i = threadIdx.x; i < 4096; i += 256) {
    int e = (x[i] >> 7) & 255;
    if (e >= 140) c++;
  }
  atomicAdd(&cnt_s, c);
  __syncthreads();
  if (threadIdx.x == 0) flag[0] = (cnt_s > 64) ? 1 : 0;
}

// ---------------- CSR build keyed by (dst*8 + rel) ----------------
__global__ void hist_kernel(const int* __restrict__ ei, const int* __restrict__ et,
                            int E, int* __restrict__ cnt8) {
  int e = blockIdx.x * 256 + threadIdx.x;
  if (e < E) atomicAdd(&cnt8[ei[E + e] * 8 + et[e]], 1);
}

// per-dst totals: sum of 8 contiguous counters (coalesced int4 x2)
__global__ void sumdst_kernel(const int* __restrict__ cnt8, int* __restrict__ dstcnt, int N) {
  int d = blockIdx.x * 256 + threadIdx.x;
  if (d >= N) return;
  const int4* p = (const int4*)(cnt8 + d * 8);
  int4 a = p[0], b = p[1];
  dstcnt[d] = a.x + a.y + a.z + a.w + b.x + b.y + b.z + b.w;
}

// proven single-block scan over N=10000 (CH=40, cheap)
__global__ __launch_bounds__(256) void scan_kernel(const int* __restrict__ cnt,
                                                   int* __restrict__ offs,
                                                   int* __restrict__ cursor, int N) {
  __shared__ int tmp[256];
  const int t = threadIdx.x;
  const int CH = (N + 255) / 256;
  const int base = t * CH;
  int s = 0;
  for (int j = 0; j < CH; j++) { int p = base + j; if (p < N) s += cnt[p]; }
  tmp[t] = s;
  __syncthreads();
  for (int od = 1; od < 256; od <<= 1) {
    int a = (t >= od) ? tmp[t - od] : 0;
    __syncthreads();
    tmp[t] += a;
    __syncthreads();
  }
  int run = tmp[t] - s;   // exclusive prefix
  for (int j = 0; j < CH; j++) {
    int p = base + j;
    if (p < N) { offs[p] = run; cursor[p] = run; run += cnt[p]; }
  }
  if (t == 255) offs[N] = tmp[255];
}

// expand dst offsets to (dst,rel) segment offsets: serial 8-prefix in registers per dst
__global__ void segoffs_kernel(const int* __restrict__ dstoffs, const int* __restrict__ cnt8,
                               int* __restrict__ offs, int* __restrict__ cursor, int N) {
  int d = blockIdx.x * 256 + threadIdx.x;
  if (d >= N) return;
  int base = dstoffs[d];
  #pragma unroll
  for (int r = 0; r < 8; r++) {
    offs[d * 8 + r] = base;
    cursor[d * 8 + r] = base;
    base += cnt8[d * 8 + r];
  }
  if (d == N - 1) offs[N * 8] = base;
}

__global__ void bucket_kernel(const int* __restrict__ ei, const int* __restrict__ et,
                              int E, int* __restrict__ cursor, int* __restrict__ bucket) {
  int e = blockIdx.x * 256 + threadIdx.x;
  if (e < E) {
    int seg = ei[E + e] * 8 + et[e];
    int pos = atomicAdd(&cursor[seg], 1);
    bucket[pos] = ei[e];   // src only; relation is the segment index
  }
}

// ---------------- transpose (emb -> embT as bf16) ----------------
__global__ void transpose_kernel(const void* __restrict__ in, u16* __restrict__ out,
                                 int R, int C, const int* __restrict__ dflag) {
  __shared__ u16 tile[64][65];
  const int f = dflag[0];
  int r0 = blockIdx.x * 64, c0 = blockIdx.y * 64;
  int t = threadIdx.x;
  #pragma unroll
  for (int k = 0; k < 16; k++) {
    int lin = t + k * 256; int rr = lin >> 6, cc = lin & 63;
    int gr = r0 + rr;
    tile[rr][cc] = (gr < R) ? f2b(ldf(in, (size_t)gr * C + c0 + cc, f)) : (u16)0;
  }
  __syncthreads();
  #pragma unroll
  for (int k = 0; k < 16; k++) {
    int lin = t + k * 256; int rr = lin >> 6, cc = lin & 63;
    int gc = r0 + cc;
    if (gc < R) out[(size_t)(c0 + rr) * R + gc] = tile[cc][rr];
  }
}

// ---------------- W-prep: WT[o][kcat], kcat = r*I+i (basis rows) then I root rows ----------------
template<int I, int O>
__global__ void wprep_kernel(const void* __restrict__ comp, const void* __restrict__ basis,
                             const void* __restrict__ root, u16* __restrict__ WT,
                             const int* __restrict__ dflag) {
  const int Kcat = 9 * I;
  const int f = dflag[0];
  int idx = blockIdx.x * 256 + threadIdx.x;
  if (idx >= Kcat * O) return;
  int o = idx % O;
  int kc = idx / O;
  float v;
  if (kc < 8 * I) {
    int r = kc / I, i = kc % I;
    float s = 0.f;
    #pragma unroll
    for (int b = 0; b < 8; b++)
      s += ldf(comp, r * 8 + b, f) * ldf(basis, ((size_t)b * I + i) * O + o, f);
    v = s;
  } else {
    int i = kc - 8 * I;
    v = ldf(root, (size_t)i * O + o, f);
  }
  WT[(size_t)o * Kcat + kc] = f2b(v);
}

// ---------------- seg-CSR gather: register accumulate, zero LDS ----------------
// s row layout: [r*I + t] = (sum over relation-r in-edges)/deg; [8*I + t] = own h row
template<int I>
__global__ void gather_seg_kernel(const u16* __restrict__ h, const int* __restrict__ offs,
                                  const int* __restrict__ bucket, u16* __restrict__ s, int node0) {
  const int d = node0 + blockIdx.x, t = threadIdx.x;   // I threads
  const int sb = d * 8;
  const int b0 = offs[sb], bend = offs[sb + 8];
  const float inv = 1.0f / (float)((bend - b0) > 1 ? (bend - b0) : 1);
  const size_t base = (size_t)blockIdx.x * (9 * I);
  #pragma unroll
  for (int r = 0; r < 8; r++) {
    int j = offs[sb + r], j1 = offs[sb + r + 1];
    float a0 = 0.f, a1 = 0.f, a2 = 0.f, a3 = 0.f;
    for (; j + 3 < j1; j += 4) {
      int s0 = bucket[j], s1 = bucket[j + 1], s2 = bucket[j + 2], s3 = bucket[j + 3];
      a0 += b2f(h[(size_t)s0 * I + t]);
      a1 += b2f(h[(size_t)s1 * I + t]);
      a2 += b2f(h[(size_t)s2 * I + t]);
      a3 += b2f(h[(size_t)s3 * I + t]);
    }
    for (; j < j1; ++j) a0 += b2f(h[(size_t)bucket[j] * I + t]);
    s[base + r * I + t] = f2b((a0 + a1 + a2 + a3) * inv);
  }
  s[base + 8 * I + t] = h[(size_t)d * I + t];
}

// ---------------- MFMA GEMM: partials[split] = A[M,K] * BT[Nout,K]^T, 128x128 tiles ----------------
// A is bf16 unless (dflagA && dflagA[0]) -> fp32 elements, converted during staging.
__global__ __launch_bounds__(256) void gemm_kernel(
    const void* __restrict__ A, int lda,
    const u16* __restrict__ BT, int ldbt,
    int M, int Nout, int K,
    int tiles_per_split, int ktiles_total,
    float* __restrict__ partials,
    const int* __restrict__ dflagA) {
  __shared__ __align__(16) u16 As[128 * 32];
  __shared__ __align__(16) u16 Bs[128 * 32];
  const int f32A = dflagA ? dflagA[0] : 0;
  const int tid = threadIdx.x;
  const int wave = tid >> 6;
  const int lane = tid & 63;
  const int quad = lane >> 4;
  const int l16 = lane & 15;
  const int m0 = blockIdx.x * 128;
  const int n0 = blockIdx.y * 128;
  const int split = blockIdx.z;
  const int wm = (wave >> 1) * 64;
  const int wn = (wave & 1) * 64;

  int kt0 = split * tiles_per_split;
  int kt1 = kt0 + tiles_per_split;
  if (kt1 > ktiles_total) kt1 = ktiles_total;

  f32x4 acc[4][4];
  #pragma unroll
  for (int mi = 0; mi < 4; mi++)
    #pragma unroll
    for (int ni = 0; ni < 4; ni++) {
      f32x4 z = {0.f, 0.f, 0.f, 0.f};
      acc[mi][ni] = z;
    }

  for (int kt = kt0; kt < kt1; ++kt) {
    const int k0 = kt * 32;
    __syncthreads();
    #pragma unroll
    for (int i = 0; i < 2; ++i) {
      int c = tid + i * 256;
      int row = c >> 2, kc = c & 3;
      int kpos = k0 + kc * 8;
      // B tile (always bf16)
      uint4 vb = {0u, 0u, 0u, 0u};
      if (kpos < K) vb = *(const uint4*)(BT + (size_t)(n0 + row) * ldbt + kpos);
      *(uint4*)&Bs[(size_t)c * 8] = vb;
      // A tile
      uint4 va = {0u, 0u, 0u, 0u};
      if (kpos < K) {
        int ga = m0 + row; if (ga > M - 1) ga = M - 1;
        if (!f32A) {
          va = *(const uint4*)((const u16*)A + (size_t)ga * lda + kpos);
        } else {
          const float* Af = (const float*)A + (size_t)ga * lda + kpos;
          float4 f0 = ((const float4*)Af)[0];
          float4 f1 = ((const float4*)Af)[1];
          va.x = (u32)f2b(f0.x) | ((u32)f2b(f0.y) << 16);
          va.y = (u32)f2b(f0.z) | ((u32)f2b(f0.w) << 16);
          va.z = (u32)f2b(f1.x) | ((u32)f2b(f1.y) << 16);
          va.w = (u32)f2b(f1.z) | ((u32)f2b(f1.w) << 16);
        }
      }
      *(uint4*)&As[(size_t)c * 8] = va;
    }
    __syncthreads();

    bf16x8 af[4], bfr[4];
    #pragma unroll
    for (int mi = 0; mi < 4; mi++)
      af[mi] = *(const bf16x8*)&As[(size_t)(wm + mi * 16 + l16) * 32 + quad * 8];
    #pragma unroll
    for (int ni = 0; ni < 4; ni++)
      bfr[ni] = *(const bf16x8*)&Bs[(size_t)(wn + ni * 16 + l16) * 32 + quad * 8];
    #pragma unroll
    for (int mi = 0; mi < 4; mi++)
      #pragma unroll
      for (int ni = 0; ni < 4; ni++)
        acc[mi][ni] = __builtin_amdgcn_mfma_f32_16x16x32_bf16(af[mi], bfr[ni], acc[mi][ni], 0, 0, 0);
  }

  #pragma unroll
  for (int mi = 0; mi < 4; mi++)
    #pragma unroll
    for (int ni = 0; ni < 4; ni++)
      #pragma unroll
      for (int jj = 0; jj < 4; jj++) {
        int row = m0 + wm + mi * 16 + quad * 4 + jj;
        int col = n0 + wn + ni * 16 + l16;
        if (row < M) partials[((size_t)split * M + row) * Nout + col] = acc[mi][ni][jj];
      }
}

// ---------------- reduce splits + optional bias + relu -> bf16 ----------------
__global__ void reduce_kernel(const float* __restrict__ partials, int S, int count,
                              int nmask, const void* __restrict__ bias, u16* __restrict__ out,
                              const int* __restrict__ dflag) {
  int idx = blockIdx.x * 256 + threadIdx.x;
  if (idx >= count) return;
  float s = 0.f;
  for (int z = 0; z < S; z++) s += partials[(size_t)z * count + idx];
  if (bias) s += ldf(bias, idx & nmask, dflag[0]);
  s = s > 0.f ? s : 0.f;
  out[idx] = f2b(s);
}

// ---------------- decoder: softmax(h2 @ wdec); output dtype follows flag ----------------
__global__ __launch_bounds__(256) void decoder_kernel(const u16* __restrict__ h2,
                                                      const void* __restrict__ wdec,
                                                      void* __restrict__ out,
                                                      const int* __restrict__ dflag) {
  __shared__ float w[128 * 32];
  __shared__ float hrow[4][128];
  const int f = dflag[0];
  int t = threadIdx.x;
  for (int i = t; i < 128 * 32; i += 256) w[i] = ldf(wdec, i, f);
  int wv = t >> 6, lane = t & 63;
  int n = blockIdx.x * 4 + wv;   // grid 2500 * 4 waves = 10000 exactly
  hrow[wv][lane * 2]     = b2f(h2[(size_t)n * 128 + lane * 2]);
  hrow[wv][lane * 2 + 1] = b2f(h2[(size_t)n * 128 + lane * 2 + 1]);
  __syncthreads();
  int half = lane >> 5, c = lane & 31;
  float sum = 0.f;
  #pragma unroll 8
  for (int k = 0; k < 64; k++) sum += hrow[wv][half * 64 + k] * w[(half * 64 + k) * 32 + c];
  sum += __shfl_xor(sum, 32);
  float mx = sum;
  #pragma unroll
  for (int m = 16; m >= 1; m >>= 1) mx = fmaxf(mx, __shfl_xor(mx, m));
  float e = __expf(sum - mx);
  float tot = e;
  #pragma unroll
  for (int m = 16; m >= 1; m >>= 1) tot += __shfl_xor(tot, m);
  float p = e / tot;
  if (half == 0) {
    if (f) ((float*)out)[(size_t)n * 32 + c] = p;
    else   ((u16*)out)[(size_t)n * 32 + c] = f2b(p);
  }
}

extern "C" void kernel_launch(void* const* d_in, const int* in_sizes, int n_in,
                              void* d_out, int out_size, void* d_ws, size_t ws_size,
                              hipStream_t stream) {
  const void* x      = d_in[0];
  const int* ei      = (const int*)d_in[1];
  const int* et      = (const int*)d_in[2];
  const void* emb    = d_in[3];
  const void* comp1  = d_in[4];
  const void* basis1 = d_in[5];
  const void* root1  = d_in[6];
  const void* bias1  = d_in[7];
  const void* comp2  = d_in[8];
  const void* basis2 = d_in[9];
  const void* root2  = d_in[10];
  const void* bias2  = d_in[11];
  const void* wdec   = d_in[12];

  const int N = N_NODES, E = E_EDGES;
  const int NSEG = N * 8;
  auto AL = [](size_t b) -> size_t { return (b + 255) & ~(size_t)255; };

  // ---- persistent arena ----
  char* base = (char*)d_ws;
  size_t off = 0;
  auto alloc = [&](size_t b) -> char* { char* p = base + off; off += AL(b); return p; };
  int* dflag  = (int*)alloc(4);
  int* offs   = (int*)alloc((size_t)(NSEG + 1) * 4);
  int* bucket = (int*)alloc((size_t)E * 4);
  u16* h0 = (u16*)alloc((size_t)N * 128 * 2);
  u16* h1 = (u16*)alloc((size_t)N * 256 * 2);
  u16* h2 = (u16*)alloc((size_t)N * 128 * 2);
  char* pool = base + off;
  size_t pool_sz = (ws_size > off) ? (ws_size - off) : 0;

  // ---- adaptive sizing (constant given ws_size -> graph-safe) ----
  int spA = 8;   // stage-A K splits; needs embT + spA*5.12MB
  while (spA > 1 && AL((size_t)128 * N * 2) + (size_t)spA * N * 128 * 4 > pool_sz) spA >>= 1;
  int nchunks = 1;
  while (nchunks < 32) {
    int Mc = (N + nchunks - 1) / nchunks;
    size_t reqL1 = AL((size_t)256 * 1152 * 2) + AL((size_t)Mc * 1152 * 2) + (size_t)2 * Mc * 256 * 4;
    size_t reqL2 = AL((size_t)128 * 2304 * 2) + AL((size_t)Mc * 2304 * 2) + (size_t)4 * Mc * 128 * 4;
    if (reqL1 <= pool_sz && reqL2 <= pool_sz) break;
    nchunks <<= 1;
  }
  const int Mc = (N + nchunks - 1) / nchunks;
  const int z1 = 2;
  const int z2 = 4;

  // ---- dtype detect ----
  detect_kernel<<<1, 256, 0, stream>>>((const u16*)x, dflag);

  // ---- CSR build keyed by (dst,rel); transient buffers in pool ----
  {
    char* p = pool;
    int* cnt8    = (int*)p;                 p += AL((size_t)NSEG * 4);
    int* cursor  = (int*)p;                 p += AL((size_t)NSEG * 4);
    int* dstcnt  = (int*)p;                 p += AL((size_t)N * 4);
    int* dstoffs = (int*)p;                 p += AL((size_t)(N + 1) * 4);
    int* dstcur  = (int*)p;                 p += AL((size_t)N * 4);
    hipMemsetAsync(cnt8, 0, (size_t)NSEG * 4, stream);
    hist_kernel<<<(E + 255) / 256, 256, 0, stream>>>(ei, et, E, cnt8);
    sumdst_kernel<<<(N + 255) / 256, 256, 0, stream>>>(cnt8, dstcnt, N);
    scan_kernel<<<1, 256, 0, stream>>>(dstcnt, dstoffs, dstcur, N);
    segoffs_kernel<<<(N + 255) / 256, 256, 0, stream>>>(dstoffs, cnt8, offs, cursor, N);
    bucket_kernel<<<(E + 255) / 256, 256, 0, stream>>>(ei, et, E, cursor, bucket);
  }

  // ---- stage A: h0 = relu(x @ emb) ----
  {
    u16* embT = (u16*)pool;
    float* pA = (float*)(pool + AL((size_t)128 * N * 2));
    transpose_kernel<<<dim3((N + 63) / 64, 2), 256, 0, stream>>>(emb, embT, N, 128, dflag);
    int ktt = (N + 31) / 32;                 // 313
    int tps = (ktt + spA - 1) / spA;
    gemm_kernel<<<dim3((N + 127) / 128, 1, spA), 256, 0, stream>>>(
        x, N, embT, N, N, 128, N, tps, ktt, pA, dflag);
    reduce_kernel<<<(N * 128 + 255) / 256, 256, 0, stream>>>(
        pA, spA, N * 128, 127, (const void*)nullptr, h0, dflag);
  }

  // ---- layer 1: gather-then-transform, I=128, O=256, Kcat=1152 ----
  {
    u16* WT1 = (u16*)pool;
    char* chunkbase = pool + AL((size_t)256 * 1152 * 2);
    wprep_kernel<128, 256><<<(1152 * 256 + 255) / 256, 256, 0, stream>>>(comp1, basis1, root1, WT1, dflag);
    for (int c = 0; c < nchunks; c++) {
      int node0 = c * Mc;
      int rows = N - node0; if (rows > Mc) rows = Mc;
      if (rows <= 0) break;
      u16* s1 = (u16*)chunkbase;
      float* p1 = (float*)(chunkbase + AL((size_t)Mc * 1152 * 2));
      gather_seg_kernel<128><<<rows, 128, 0, stream>>>(h0, offs, bucket, s1, node0);
      gemm_kernel<<<dim3((rows + 127) / 128, 2, z1), 256, 0, stream>>>(
          s1, 1152, WT1, 1152, rows, 256, 1152, (36 + z1 - 1) / z1, 36, p1, (const int*)nullptr);
      reduce_kernel<<<(rows * 256 + 255) / 256, 256, 0, stream>>>(
          p1, z1, rows * 256, 255, bias1, h1 + (size_t)node0 * 256, dflag);
    }
  }

  // ---- layer 2: gather-then-transform, I=256, O=128, Kcat=2304 ----
  {
    u16* WT2 = (u16*)pool;
    char* chunkbase = pool + AL((size_t)128 * 2304 * 2);
    wprep_kernel<256, 128><<<(2304 * 128 + 255) / 256, 256, 0, stream>>>(comp2, basis2, root2, WT2, dflag);
    for (int c = 0; c < nchunks; c++) {
      int node0 = c * Mc;
      int rows = N - node0; if (rows > Mc) rows = Mc;
      if (rows <= 0) break;
      u16* s2 = (u16*)chunkbase;
      float* p2 = (float*)(chunkbase + AL((size_t)Mc * 2304 * 2));
      gather_seg_kernel<256><<<rows, 256, 0, stream>>>(h1, offs, bucket, s2, node0);
      gemm_kernel<<<dim3((rows + 127) / 128, 1, z2), 256, 0, stream>>>(
          s2, 2304, WT2, 2304, rows, 128, 2304, (72 + z2 - 1) / z2, 72, p2, (const int*)nullptr);
      reduce_kernel<<<(rows * 128 + 255) / 256, 256, 0, stream>>>(
          p2, z2, rows * 128, 127, bias2, h2 + (size_t)node0 * 128, dflag);
    }
  }

  // ---- decoder + softmax ----
  decoder_kernel<<<N / 4, 256, 0, stream>>>(h2, wdec, d_out, dflag);
}